// Round 8
// baseline (4906.190 us; speedup 1.0000x reference)
//
#include <hip/hip_runtime.h>
#include <hip/hip_bf16.h>

#define NLAYERS 6
#define BB 8
#define TT 512
#define DMODEL 2048
#define DSTATE 128
#define DCONV 4
#define DINNER 4096
#define NTOK (BB*TT)              // 4096 tokens

typedef __bf16 bf16x8 __attribute__((ext_vector_type(8)));
typedef float floatx4 __attribute__((ext_vector_type(4)));
typedef float floatx16 __attribute__((ext_vector_type(16)));
typedef unsigned short ushort8v __attribute__((ext_vector_type(8)));
typedef unsigned short ushort4v __attribute__((ext_vector_type(4)));

__device__ __forceinline__ float bf2f(unsigned short u) {
    return __uint_as_float(((unsigned)u) << 16);
}
__device__ __forceinline__ unsigned short f2bf(float f) {
    unsigned u = __float_as_uint(f);
    unsigned r = u + 0x7FFFu + ((u >> 16) & 1u);   // round-nearest-even
    return (unsigned short)(r >> 16);
}
__device__ __forceinline__ float siluf(float x) { return x / (1.f + __expf(-x)); }
__device__ __forceinline__ float softplusf(float x) {
    return fmaxf(x, 0.f) + log1pf(__expf(-fabsf(x)));
}

__device__ __forceinline__ void gload16(const void* g, void* l) {
    __builtin_amdgcn_global_load_lds(
        (const __attribute__((address_space(1))) void*)g,
        (__attribute__((address_space(3))) void*)l, 16, 0, 0);
}

// ---------------- fp32 -> bf16 weight conversion ----------------
__global__ __launch_bounds__(256) void cvt_kernel(const float* __restrict__ s,
                                                  unsigned short* __restrict__ d, int n) {
    int i = (blockIdx.x * blockDim.x + threadIdx.x) * 4;
    if (i < n) {
        float4 v = *(const float4*)(s + i);
        ushort4v o = {f2bf(v.x), f2bf(v.y), f2bf(v.z), f2bf(v.w)};
        *(ushort4v*)(d + i) = o;
    }
}

// ---------------- fused (p0+p1+h) + LayerNorm: fp32 in -> h fp32 + xn bf16 ----------------
__global__ __launch_bounds__(256) void ln3_kernel(const float* __restrict__ p0,
                                                  const float* __restrict__ p1,
                                                  const float* __restrict__ hin,
                                                  const float* __restrict__ g,
                                                  const float* __restrict__ b,
                                                  int hasP,
                                                  float* __restrict__ hout,
                                                  unsigned short* __restrict__ out) {
    const int row = blockIdx.x;
    const long rb = (long)row * DMODEL;
    const int base = threadIdx.x * 8;
    float vv[8];
    float4 v0 = *(const float4*)(hin + rb + base);
    float4 v1 = *(const float4*)(hin + rb + base + 4);
    vv[0]=v0.x; vv[1]=v0.y; vv[2]=v0.z; vv[3]=v0.w;
    vv[4]=v1.x; vv[5]=v1.y; vv[6]=v1.z; vv[7]=v1.w;
    if (hasP) {
        float4 a0 = *(const float4*)(p0 + rb + base);
        float4 a1 = *(const float4*)(p0 + rb + base + 4);
        float4 c0 = *(const float4*)(p1 + rb + base);
        float4 c1 = *(const float4*)(p1 + rb + base + 4);
        vv[0]+=a0.x+c0.x; vv[1]+=a0.y+c0.y; vv[2]+=a0.z+c0.z; vv[3]+=a0.w+c0.w;
        vv[4]+=a1.x+c1.x; vv[5]+=a1.y+c1.y; vv[6]+=a1.z+c1.z; vv[7]+=a1.w+c1.w;
        float4 w0 = {vv[0],vv[1],vv[2],vv[3]}, w1 = {vv[4],vv[5],vv[6],vv[7]};
        *(float4*)(hout + rb + base) = w0;
        *(float4*)(hout + rb + base + 4) = w1;
    }
    float s = 0.f, s2 = 0.f;
#pragma unroll
    for (int j = 0; j < 8; j++) { s += vv[j]; s2 += vv[j] * vv[j]; }
#pragma unroll
    for (int off = 32; off >= 1; off >>= 1) {
        s += __shfl_xor(s, off);
        s2 += __shfl_xor(s2, off);
    }
    __shared__ float red[8];
    int wave = threadIdx.x >> 6, lane = threadIdx.x & 63;
    if (lane == 0) { red[wave] = s; red[4 + wave] = s2; }
    __syncthreads();
    s = red[0] + red[1] + red[2] + red[3];
    s2 = red[4] + red[5] + red[6] + red[7];
    float mu = s * (1.f / DMODEL);
    float var = s2 * (1.f / DMODEL) - mu * mu;
    float rs = rsqrtf(var + 1e-5f);
    ushort8v ov;
#pragma unroll
    for (int j = 0; j < 8; j++)
        ov[j] = f2bf((vv[j] - mu) * rs * g[base + j] + b[base + j]);
    *(ushort8v*)&out[rb + base] = ov;
}

// ---------------- final combine: out = p0 + p1 + h ----------------
__global__ __launch_bounds__(256) void combine3_kernel(const float* __restrict__ p0,
                                                       const float* __restrict__ p1,
                                                       const float* __restrict__ h,
                                                       float* __restrict__ out) {
    long i = (long)(blockIdx.x * blockDim.x + threadIdx.x) * 4;
    float4 a = *(const float4*)(p0 + i);
    float4 b = *(const float4*)(p1 + i);
    float4 c = *(const float4*)(h + i);
    float4 o = {a.x+b.x+c.x, a.y+b.y+c.y, a.z+b.z+c.z, a.w+b.w+c.w};
    *(float4*)(out + i) = o;
}

// ---------------- bc = sum of 4 K-split partials ----------------
__global__ __launch_bounds__(256) void bcsum_kernel(const float* __restrict__ bcp,
                                                    float* __restrict__ bc) {
    long i = (long)(blockIdx.x * blockDim.x + threadIdx.x) * 4;
    const long S = (long)NTOK * 256;
    float4 a = *(const float4*)(bcp + i);
    float4 b = *(const float4*)(bcp + S + i);
    float4 c = *(const float4*)(bcp + 2*S + i);
    float4 d = *(const float4*)(bcp + 3*S + i);
    float4 o = {a.x+b.x+c.x+d.x, a.y+b.y+c.y+d.y, a.z+b.z+c.z+d.z, a.w+b.w+c.w+d.w};
    *(float4*)(bc + i) = o;
}

// ============ 256x256 MFMA GEMM, 32x32x16 frags, 3-buffer LDS, 1 barrier/K-tile ============
// 512 thr, 8 waves: wm=w>>2 (M 128-band), wn=w&3 (N 64-band). Wave tile 128x64,
// acc[4][2] of 32x32 frags (floatx16). BK=32; LDS buffer = A 16KB + B 16KB = 32KB, x3 = 96KB.
// LDS packs 2 matrix rows per 128B lds-row; 16B chunk swizzle: stored slot = c2 ^ (ldsrow&7),
// c2 = (r&1)*4 + chunk (3-bit XOR -> conflict-free class, verified 0-conflict since R3).
// Per tile: vmcnt(4) [tile t landed, t+1 in flight]; barrier; stage t+2 (4 gload_lds);
// issue 12 ds_reads (both ksteps); lgkm(6) -> 8 MFMA(k0) while k1 reads fly; lgkm(0) -> 8 MFMA(k1).
// Swapped operands: mfma(Bfrag, Afrag) -> lane&31 = M-row, reg-groups = 4 consecutive N-cols.
// EPI: 0 = bf16 store (W_in); 1 = softplus-sum -> dmean atomics (W_dt); 2 = bc K-split partial
// (W_xp, kpart = rest); 3 = fp32 K-split partial (W_out, kpart = rest>>3).

#define BARR __builtin_amdgcn_s_barrier()
#define SCHB __builtin_amdgcn_sched_barrier(0)
#define PRIO1 __builtin_amdgcn_s_setprio(1)
#define PRIO0 __builtin_amdgcn_s_setprio(0)
#define VM4   asm volatile("s_waitcnt vmcnt(4)")
#define LGKM6 do { asm volatile("s_waitcnt lgkmcnt(6)"); SCHB; } while(0)
#define LGKM0 do { asm volatile("s_waitcnt lgkmcnt(0)"); SCHB; } while(0)

template <int EPI>
__global__ __launch_bounds__(512, 1) void gemm32(const unsigned short* __restrict__ A,
                                                 const unsigned short* __restrict__ B,
                                                 int Kstr, int RY, int KT, int ldc,
                                                 unsigned short* __restrict__ obf,
                                                 float* __restrict__ of0,
                                                 float* __restrict__ of1,
                                                 const float* __restrict__ bias,
                                                 float* __restrict__ dmean) {
    __shared__ __align__(16) char lds[3 * 32768];
    const int tid = threadIdx.x;
    const int w = tid >> 6, lane = tid & 63;
    const int wm = w >> 2, wn = w & 3;

    // grid decode: block -> XCD b&7; per-XCD by-rows; rest encodes bx / kpart
    const int xcd = blockIdx.x & 7;
    const int l = blockIdx.x >> 3;
    const int by = xcd * RY + (l % RY);
    const int rest = l / RY;
    int bx = 0, kpart = 0;
    if constexpr (EPI == 0 || EPI == 1) { bx = rest; }
    else if constexpr (EPI == 2) { kpart = rest; }
    else { bx = rest & 7; kpart = rest >> 3; }
    const long rowBase = (long)by * 256;
    const long colBase = (long)bx * 256;
    const long K0 = (long)kpart * KT * 32;

    // frag-read lane constants (c2 = (lane&1)*4 + ks*2 + (lane>>5), XOR (lane>>1)&7)
    const int l1 = lane & 1, l5 = lane >> 5, lh = (lane >> 1) & 7;
    const int cb0 = (((l1 << 2) | l5) ^ lh) * 16;
    const int cb1 = (((l1 << 2) | 2 | l5) ^ lh) * 16;
    const int lsub = (lane & 31) >> 1;
    const char* rdA = lds + (wm * 64 + lsub) * 128;
    const char* rdB = lds + 16384 + (wn * 32 + lsub) * 128;

    // staging lane map (linear LDS dest, pre-swizzled global source)
    const int c2s = (lane & 7) ^ (lane >> 3);
    const int rS = w * 32 + 2 * (lane >> 3) + (c2s >> 2);
    const size_t Kb2 = (size_t)Kstr * 2;
    const char* pA = (const char*)A + (size_t)(rowBase + rS) * Kb2 + (c2s & 3) * 16 + (size_t)K0 * 2;
    const char* pB = (const char*)B + (size_t)(colBase + rS) * Kb2 + (c2s & 3) * 16 + (size_t)K0 * 2;
    char* ldsA = lds + w * 2048;
    char* ldsB = lds + 16384 + w * 2048;

    floatx16 acc[4][2];
#pragma unroll
    for (int m = 0; m < 4; m++)
#pragma unroll
        for (int n = 0; n < 2; n++) acc[m][n] = (floatx16)(0.0f);
    bf16x8 a0[4], a1[4], b0[2], b1[2];

#define STAGE(BS, TOFF) do { \
    gload16(pA + (TOFF), ldsA + (BS)); \
    gload16(pA + (TOFF) + 16 * Kb2, ldsA + (BS) + 1024); \
    gload16(pB + (TOFF), ldsB + (BS)); \
    gload16(pB + (TOFF) + 16 * Kb2, ldsB + (BS) + 1024); } while(0)

#define RD(AF, BF, BO, CB) do { _Pragma("unroll") \
  for (int mi_ = 0; mi_ < 4; mi_++) AF[mi_] = *(const bf16x8*)(rdA + (BO) + mi_ * 2048 + (CB)); \
  _Pragma("unroll") \
  for (int ni_ = 0; ni_ < 2; ni_++) BF[ni_] = *(const bf16x8*)(rdB + (BO) + ni_ * 2048 + (CB)); } while(0)

#define MM8(AF, BF) do { _Pragma("unroll") \
  for (int mi_ = 0; mi_ < 4; mi_++) { _Pragma("unroll") \
    for (int ni_ = 0; ni_ < 2; ni_++) \
      acc[mi_][ni_] = __builtin_amdgcn_mfma_f32_32x32x16_bf16(BF[ni_], AF[mi_], acc[mi_][ni_], 0, 0, 0); } } while(0)

    // prologue: tiles 0 and 1 (8 loads in flight per wave)
    STAGE(0, 0);
    STAGE(32768, 64);

    for (int t = 0; t < KT; t++) {
        const long bo = (long)(t % 3) * 32768;
        const long bs = (long)((t + 2) % 3) * 32768;
        const size_t toff = (size_t)((t + 2 < KT) ? (t + 2) : (KT - 1)) * 64;
        VM4;                  // my tile-t stage landed (t+1's 4 remain in flight)
        BARR;                 // everyone's landed; everyone done reading buf[(t+2)%3]
        STAGE(bs, toff);      // tile t+2 -> freed buffer
        RD(a0, b0, bo, cb0);
        RD(a1, b1, bo, cb1);
        SCHB;
        LGKM6;                // k0 frags ready; k1 reads stay in flight
        PRIO1; MM8(a0, b0); PRIO0;
        LGKM0;
        PRIO1; MM8(a1, b1); PRIO0;
    }
#undef STAGE
#undef RD
#undef MM8

    // ---------------- epilogue ----------------
    // swapped C/D: M-row = lane&31; N-col = (reg&3) + 8*(reg>>2) + 4*(lane>>5)
    const int mrow = lane & 31, nq = (lane >> 5) * 4;
    if constexpr (EPI == 0) {
#pragma unroll
        for (int mi = 0; mi < 4; mi++) {
            long row = rowBase + wm * 128 + mi * 32 + mrow;
#pragma unroll
            for (int ni = 0; ni < 2; ni++)
#pragma unroll
                for (int q = 0; q < 4; q++) {
                    long col = colBase + wn * 64 + ni * 32 + q * 8 + nq;
                    ushort4v o = {f2bf(acc[mi][ni][4*q]), f2bf(acc[mi][ni][4*q+1]),
                                  f2bf(acc[mi][ni][4*q+2]), f2bf(acc[mi][ni][4*q+3])};
                    *(ushort4v*)&obf[row * ldc + col] = o;
                }
        }
    } else if constexpr (EPI == 1) {
        // delta: softplus(acc + b_dt) summed over the wave's 64 cols -> dmean atomics
#pragma unroll
        for (int mi = 0; mi < 4; mi++) {
            long row = rowBase + wm * 128 + mi * 32 + mrow;
            float s = 0.f;
#pragma unroll
            for (int ni = 0; ni < 2; ni++)
#pragma unroll
                for (int q = 0; q < 4; q++) {
                    float4 bi = *(const float4*)&bias[colBase + wn * 64 + ni * 32 + q * 8 + nq];
                    s += softplusf(acc[mi][ni][4*q]   + bi.x);
                    s += softplusf(acc[mi][ni][4*q+1] + bi.y);
                    s += softplusf(acc[mi][ni][4*q+2] + bi.z);
                    s += softplusf(acc[mi][ni][4*q+3] + bi.w);
                }
            s += __shfl_xor(s, 32);
            if (lane < 32)
                atomicAdd(&dmean[row], s);
        }
    } else if constexpr (EPI == 2) {
        // W_xp K-split partial -> bcp[kpart][row][256]
        float* op = of0 + (long)kpart * NTOK * 256;
#pragma unroll
        for (int mi = 0; mi < 4; mi++) {
            long row = rowBase + wm * 128 + mi * 32 + mrow;
#pragma unroll
            for (int ni = 0; ni < 2; ni++)
#pragma unroll
                for (int q = 0; q < 4; q++) {
                    long col = wn * 64 + ni * 32 + q * 8 + nq;
                    floatx4 o = {acc[mi][ni][4*q], acc[mi][ni][4*q+1],
                                 acc[mi][ni][4*q+2], acc[mi][ni][4*q+3]};
                    *(floatx4*)&op[row * 256 + col] = o;
                }
        }
    } else {
        // W_out K-split partial -> p0/p1
        float* op = (kpart == 0) ? of0 : of1;
#pragma unroll
        for (int mi = 0; mi < 4; mi++) {
            long row = rowBase + wm * 128 + mi * 32 + mrow;
#pragma unroll
            for (int ni = 0; ni < 2; ni++)
#pragma unroll
                for (int q = 0; q < 4; q++) {
                    long col = colBase + wn * 64 + ni * 32 + q * 8 + nq;
                    floatx4 o = {acc[mi][ni][4*q], acc[mi][ni][4*q+1],
                                 acc[mi][ni][4*q+2], acc[mi][ni][4*q+3]};
                    *(floatx4*)&op[row * ldc + col] = o;
                }
        }
    }
}

// ---------------- causal depthwise conv1d + bias + silu ----------------
__global__ __launch_bounds__(256) void conv_silu_kernel(const unsigned short* __restrict__ xr,
                                                        const float* __restrict__ w,
                                                        const float* __restrict__ cb,
                                                        unsigned short* __restrict__ xc) {
    int idx = blockIdx.x * blockDim.x + threadIdx.x;   // NTOK * 512
    int d0 = (idx & 511) * 8;
    int bt = idx >> 9;
    int t = bt & (TT - 1);
    float acc[8];
#pragma unroll
    for (int j = 0; j < 8; j++) acc[j] = cb[d0 + j];
#pragma unroll
    for (int k = 0; k < DCONV; k++) {
        int ts = t - (DCONV - 1) + k;
        if (ts < 0) continue;
        ushort8v v = *(const ushort8v*)&xr[(long)(bt - (DCONV - 1) + k) * (2 * DINNER) + d0];
#pragma unroll
        for (int j = 0; j < 8; j++) acc[j] += bf2f(v[j]) * w[(d0 + j) * DCONV + k];
    }
    ushort8v ov;
#pragma unroll
    for (int j = 0; j < 8; j++) ov[j] = f2bf(siluf(acc[j]));
    *(ushort8v*)&xc[(long)bt * DINNER + d0] = ov;
}

// ---------------- sequential selective-scan (1 wave per batch) ----------------
__global__ void scan_kernel(const float* __restrict__ dmean, const float* __restrict__ bcmat,
                            const float* __restrict__ A_log, float* __restrict__ ys) {
    int b = blockIdx.x, lane = threadIdx.x;   // 64 lanes, 2 states each
    float A0 = -expf(A_log[lane]);
    float A1 = -expf(A_log[lane + 64]);
    float h0 = 0.f, h1 = 0.f;
    const float inv = 1.f / (float)DINNER;
    const float* rowp = bcmat + (long)b * TT * (2 * DSTATE);
    const float* dmp = dmean + b * TT;
    float B0 = rowp[lane], B1 = rowp[64 + lane];
    float C0 = rowp[128 + lane], C1 = rowp[192 + lane];
    float DM = dmp[0];
    for (int t = 0; t < TT; t++) {
        float nB0 = 0.f, nB1 = 0.f, nC0 = 0.f, nC1 = 0.f, nDM = 0.f;
        if (t + 1 < TT) {
            const float* nx = rowp + (long)(t + 1) * 256;
            nB0 = nx[lane]; nB1 = nx[64 + lane];
            nC0 = nx[128 + lane]; nC1 = nx[192 + lane];
            nDM = dmp[t + 1];
        }
        float dm = DM * inv;
        h0 = h0 * __expf(dm * A0) + B0;
        h1 = h1 * __expf(dm * A1) + B1;
        float v = h0 * C0 + h1 * C1;
#pragma unroll
        for (int off = 32; off >= 1; off >>= 1) v += __shfl_xor(v, off);
        if (lane == 0) ys[b * TT + t] = v;
        B0 = nB0; B1 = nB1; C0 = nC0; C1 = nC1; DM = nDM;
    }
}

// ---------------- y = (ys + D_skip*xc) * silu(res) ----------------
__global__ __launch_bounds__(256) void ycomb_kernel(const float* __restrict__ ys,
                                                    const unsigned short* __restrict__ xc,
                                                    const unsigned short* __restrict__ xr,
                                                    const float* __restrict__ dskip,
                                                    unsigned short* __restrict__ yc) {
    int idx = blockIdx.x * blockDim.x + threadIdx.x;
    int d0 = (idx & 511) * 8;
    int bt = idx >> 9;
    float y = ys[bt];
    ushort8v xcv = *(const ushort8v*)&xc[(long)bt * DINNER + d0];
    ushort8v rv = *(const ushort8v*)&xr[(long)bt * (2 * DINNER) + DINNER + d0];
    ushort8v ov;
#pragma unroll
    for (int j = 0; j < 8; j++) {
        float val = (y + dskip[d0 + j] * bf2f(xcv[j])) * siluf(bf2f(rv[j]));
        ov[j] = f2bf(val);
    }
    *(ushort8v*)&yc[(long)bt * DINNER + d0] = ov;
}

extern "C" void kernel_launch(void* const* d_in, const int* in_sizes, int n_in,
                              void* d_out, int out_size, void* d_ws, size_t ws_size,
                              hipStream_t stream) {
    const float* x      = (const float*)d_in[0];
    const float* ln_g   = (const float*)d_in[1];
    const float* ln_b   = (const float*)d_in[2];
    const float* W_in   = (const float*)d_in[3];
    const float* conv_w = (const float*)d_in[4];
    const float* conv_b = (const float*)d_in[5];
    const float* W_xp   = (const float*)d_in[6];
    const float* W_dt   = (const float*)d_in[7];
    const float* b_dt   = (const float*)d_in[8];
    const float* A_log  = (const float*)d_in[9];
    const float* D_skip = (const float*)d_in[10];
    const float* W_out  = (const float*)d_in[11];
    float* out = (float*)d_out;

    // workspace carve
    char* ws = (char*)d_ws;
    const size_t nWin  = (size_t)2 * DINNER * DMODEL;
    const size_t nWdt  = (size_t)DINNER * DINNER;
    const size_t nWxp  = (size_t)2 * DSTATE * DINNER;
    const size_t nWout = (size_t)DMODEL * DINNER;

    unsigned short* wb_in  = (unsigned short*)ws; ws += nWin * 2;
    unsigned short* wb_dt  = (unsigned short*)ws; ws += nWdt * 2;
    unsigned short* wb_xp  = (unsigned short*)ws; ws += nWxp * 2;
    unsigned short* wb_out = (unsigned short*)ws; ws += nWout * 2;
    unsigned short* xn = (unsigned short*)ws; ws += (size_t)NTOK * DMODEL * 2;
    unsigned short* xr = (unsigned short*)ws; ws += (size_t)NTOK * 2 * DINNER * 2;
    unsigned short* xc = (unsigned short*)ws; ws += (size_t)NTOK * DINNER * 2;
    unsigned short* yc = (unsigned short*)ws; ws += (size_t)NTOK * DINNER * 2;
    float* bc    = (float*)ws; ws += (size_t)NTOK * 2 * DSTATE * 4;
    float* bcp   = (float*)ws; ws += (size_t)4 * NTOK * 2 * DSTATE * 4;
    float* dmean = (float*)ws; ws += (size_t)NTOK * 4;
    float* ysb   = (float*)ws; ws += (size_t)NTOK * 4;
    float* h0    = (float*)ws; ws += (size_t)NTOK * DMODEL * 4;
    float* h1    = (float*)ws; ws += (size_t)NTOK * DMODEL * 4;
    // p0/p1 alias the xr region (xr dead after ycomb; W_out runs after ycomb;
    // next layer's ln3 consumes p0/p1 BEFORE W_in rewrites xr)
    float* p0 = (float*)xr;
    float* p1 = (float*)xr + (size_t)NTOK * DMODEL;

    const float* hprev = x;
    for (int lay = 0; lay < NLAYERS; lay++) {
        cvt_kernel<<<(int)(nWin / 1024), 256, 0, stream>>>(W_in + (size_t)lay * nWin, wb_in, (int)nWin);
        cvt_kernel<<<(int)(nWdt / 1024), 256, 0, stream>>>(W_dt + (size_t)lay * nWdt, wb_dt, (int)nWdt);
        cvt_kernel<<<(int)(nWxp / 1024), 256, 0, stream>>>(W_xp + (size_t)lay * nWxp, wb_xp, (int)nWxp);
        cvt_kernel<<<(int)(nWout / 1024), 256, 0, stream>>>(W_out + (size_t)lay * nWout, wb_out, (int)nWout);

        hipMemsetAsync(dmean, 0, (size_t)NTOK * 4, stream);

        // 1) fused residual-combine + LayerNorm (layer 0: plain LN on x)
        float* hcur = (lay & 1) ? h1 : h0;
        ln3_kernel<<<NTOK, 256, 0, stream>>>(p0, p1, hprev,
                                             ln_g + lay * DMODEL, ln_b + lay * DMODEL,
                                             lay > 0 ? 1 : 0, hcur, xn);
        if (lay > 0) hprev = hcur;

        // 2) x_and_res = xn @ W_in^T  [4096 x 8192], K=2048: grid 16y x 32x = 512 (2 rounds exact)
        gemm32<0><<<512, 512, 0, stream>>>(xn, wb_in, DMODEL, 2, 64, 2 * DINNER,
                                           xr, nullptr, nullptr, nullptr, nullptr);

        // 3) causal depthwise conv + silu
        conv_silu_kernel<<<NTOK * 512 / 256, 256, 0, stream>>>(
            xr, conv_w + (size_t)lay * DINNER * DCONV, conv_b + (size_t)lay * DINNER, xc);

        // 4a) W_dt GEMM [4096 x 4096], K=4096 full: grid 16x16 = 256 (1 round exact), delta epilogue
        gemm32<1><<<256, 512, 0, stream>>>(xc, wb_dt, DINNER, 2, 128, 0,
                                           nullptr, nullptr, nullptr,
                                           b_dt + (size_t)lay * DINNER, dmean);

        // 4b) W_xp GEMM [4096 x 256], K-split x4 (KT=32 each): grid 16y x 4k = 64
        gemm32<2><<<64, 512, 0, stream>>>(xc, wb_xp, DINNER, 2, 32, 0,
                                          nullptr, bcp, nullptr, nullptr, nullptr);

        // 4c) bc = sum of partials
        bcsum_kernel<<<(NTOK * 256 / 4) / 256, 256, 0, stream>>>(bcp, bc);

        // 5) sequential scan -> ys
        scan_kernel<<<BB, 64, 0, stream>>>(dmean, bc, A_log + (size_t)lay * DSTATE, ysb);

        // 6) y = (ys + D_skip*xc) * silu(res)   (reads xr res-half; xr dead after this)
        ycomb_kernel<<<NTOK * 512 / 256, 256, 0, stream>>>(
            ysb, xc, xr, D_skip + (size_t)lay * DINNER, yc);

        // 7) W_out partials [4096 x 2048], K-split x2 (KT=64): grid 16y x 8x x 2k = 256 (1 round)
        gemm32<3><<<256, 512, 0, stream>>>(yc, wb_out, DINNER, 2, 64, DMODEL,
                                           nullptr, p0, p1, nullptr, nullptr);
    }

    // final: out = p0 + p1 + h5
    combine3_kernel<<<(NTOK * DMODEL / 4) / 256, 256, 0, stream>>>(p0, p1, hprev, out);

    (void)in_sizes; (void)n_in; (void)out_size; (void)ws_size;
}